// Round 2
// baseline (388.965 us; speedup 1.0000x reference)
//
#include <hip/hip_runtime.h>
#include <stdint.h>

#define Bq 2
#define Tq 1024
#define Cq 1024
#define Hq 16
#define HDq 64

typedef unsigned int uint32;

// ---------------- GEMM: C = A[M,K] @ W[K,N], f32 row-major ----------------
// 128x64 tile, BK=16, 256 threads, 8x4 microtile. grid.z selects (W,C) pair.
__global__ __launch_bounds__(256) void gemm3_f32(
    const float* __restrict__ A,
    const float* __restrict__ W0, const float* __restrict__ W1, const float* __restrict__ W2,
    float* __restrict__ C0, float* __restrict__ C1, float* __restrict__ C2,
    int M, int N, int K)
{
  const float* __restrict__ W = (blockIdx.z == 0) ? W0 : ((blockIdx.z == 1) ? W1 : W2);
  float* __restrict__ C = (blockIdx.z == 0) ? C0 : ((blockIdx.z == 1) ? C1 : C2);
  __shared__ float As[16][128];
  __shared__ float Bs[16][64];
  const int t = threadIdx.x;
  const int tx = t & 15, ty = t >> 4;
  const int m0 = blockIdx.x * 128, n0 = blockIdx.y * 64;
  float acc[8][4];
#pragma unroll
  for (int i = 0; i < 8; i++)
#pragma unroll
    for (int j = 0; j < 4; j++) acc[i][j] = 0.f;

  for (int k0 = 0; k0 < K; k0 += 16) {
#pragma unroll
    for (int u = 0; u < 2; u++) {
      int f = t + u * 256;
      int row = f >> 2, c4 = (f & 3) << 2;
      float4 va = *reinterpret_cast<const float4*>(&A[(size_t)(m0 + row) * K + k0 + c4]);
      As[c4 + 0][row] = va.x;
      As[c4 + 1][row] = va.y;
      As[c4 + 2][row] = va.z;
      As[c4 + 3][row] = va.w;
    }
    {
      int row = t >> 4, c4 = (t & 15) << 2;
      *reinterpret_cast<float4*>(&Bs[row][c4]) =
          *reinterpret_cast<const float4*>(&W[(size_t)(k0 + row) * N + n0 + c4]);
    }
    __syncthreads();
#pragma unroll
    for (int kk = 0; kk < 16; kk++) {
      float4 a0 = *reinterpret_cast<const float4*>(&As[kk][ty * 8]);
      float4 a1 = *reinterpret_cast<const float4*>(&As[kk][ty * 8 + 4]);
      float4 bb = *reinterpret_cast<const float4*>(&Bs[kk][tx * 4]);
      float a[8] = {a0.x, a0.y, a0.z, a0.w, a1.x, a1.y, a1.z, a1.w};
      float b[4] = {bb.x, bb.y, bb.z, bb.w};
#pragma unroll
      for (int i = 0; i < 8; i++)
#pragma unroll
        for (int j = 0; j < 4; j++) acc[i][j] = fmaf(a[i], b[j], acc[i][j]);
    }
    __syncthreads();
  }
#pragma unroll
  for (int i = 0; i < 8; i++) {
    float4 o = {acc[i][0], acc[i][1], acc[i][2], acc[i][3]};
    *reinterpret_cast<float4*>(&C[(size_t)(m0 + ty * 8 + i) * N + n0 + tx * 4]) = o;
  }
}

// ---------------- RoPE + RMS + hard digits (q,k -> packed bytes) ----------
// One 32-lane group per (b,t,h) unit; lane d pairs (d, d+32).
// digits are sign(qn . Wd[:,j]) -- invariant to the positive rsqrt scale.
__global__ __launch_bounds__(256) void digits_kernel(
    const float* __restrict__ q, const float* __restrict__ k,
    const float* __restrict__ cosT, const float* __restrict__ sinT,
    const float* __restrict__ Wdq, const float* __restrict__ Wdk,
    uint8_t* __restrict__ dqb, uint8_t* __restrict__ dkb)
{
  const int t = threadIdx.x;
  const int lane = t & 31;
  const int u = blockIdx.x * 8 + (t >> 5);     // (b*T + tt)*H + h
  const int h = u & (Hq - 1);
  const int tt = (u >> 4) & (Tq - 1);
  const int b = u >> 14;
  const size_t base = (size_t)u * HDq;
  const float c = cosT[tt * 32 + lane];
  const float s = sinT[tt * 32 + lane];

  // ---- q ----
  {
    float x1 = q[base + lane], x2 = q[base + lane + 32];
    float r1 = x1 * c + x2 * s;
    float r2 = x2 * c - x1 * s;
    float ss = r1 * r1 + r2 * r2;
#pragma unroll
    for (int off = 16; off; off >>= 1) ss += __shfl_xor(ss, off, 32);
    float inv = rsqrtf(ss * (1.f / 64.f) + 1e-6f);
    r1 *= inv; r2 *= inv;
    uint32 bits = 0;
#pragma unroll
    for (int j = 0; j < 8; j++) {
      float p = r1 * Wdq[lane * 8 + j] + r2 * Wdq[(lane + 32) * 8 + j];
#pragma unroll
      for (int off = 16; off; off >>= 1) p += __shfl_xor(p, off, 32);
      bits |= (p > 0.f ? 1u : 0u) << j;
    }
    if (lane == 0) dqb[((size_t)b * Hq + h) * Tq + tt] = (uint8_t)bits;
  }
  // ---- k ----
  {
    float x1 = k[base + lane], x2 = k[base + lane + 32];
    float r1 = x1 * c + x2 * s;
    float r2 = x2 * c - x1 * s;
    float ss = r1 * r1 + r2 * r2;
#pragma unroll
    for (int off = 16; off; off >>= 1) ss += __shfl_xor(ss, off, 32);
    float inv = rsqrtf(ss * (1.f / 64.f) + 1e-6f);
    r1 *= inv; r2 *= inv;
    uint32 bits = 0;
#pragma unroll
    for (int j = 0; j < 8; j++) {
      float p = r1 * Wdk[lane * 8 + j] + r2 * Wdk[(lane + 32) * 8 + j];
#pragma unroll
      for (int off = 16; off; off >>= 1) p += __shfl_xor(p, off, 32);
      bits |= (p > 0.f ? 1u : 0u) << j;
    }
    if (lane == 0) dkb[((size_t)b * Hq + h) * Tq + tt] = (uint8_t)bits;
  }
}

// ---------------- dense causal ultrametric attention ----------------------
// block = 256 thr = 4 waves; one 64-query tile per block; waves take key
// tiles mod 4; each wave stages its own v tile in its LDS quadrant.
// w(q,k) = 2^lcp = (x==0) ? 256 : (x & -x), x = dq ^ dk.
__global__ __launch_bounds__(256) void attn_dense(
    const float* __restrict__ v, const uint8_t* __restrict__ dqb,
    const uint8_t* __restrict__ dkb, float* __restrict__ y)
{
  __shared__ float vs[4][64][64];   // 64 KB
  const int t = threadIdx.x;
  const int wid = t >> 6;
  const int lane = t & 63;
  const int qt = blockIdx.x, h = blockIdx.y, b = blockIdx.z;
  const int qbase = qt * 64;
  const int q = qbase + lane;
  const uint32 myd = dqb[((size_t)b * Hq + h) * Tq + q];
  const size_t vbh = ((size_t)b * Tq * Hq + h) * HDq;
  const size_t dkbase = ((size_t)b * Hq + h) * Tq;
  float num[64];
#pragma unroll
  for (int d = 0; d < 64; d++) num[d] = 0.f;
  float den = 0.f;
  const int ntiles = qt + 1;
  const int rounds = (ntiles + 3) >> 2;

  for (int r = 0; r < rounds; r++) {
    const int ti = r * 4 + wid;
    const bool active = ti < ntiles;
    uint32 dkw = 0;
    if (active) {
#pragma unroll
      for (int it = 0; it < 16; it++) {
        int row = it * 4 + (lane >> 4);
        int f4 = (lane & 15) << 2;
        *reinterpret_cast<float4*>(&vs[wid][row][f4]) =
            *reinterpret_cast<const float4*>(
                &v[vbh + (size_t)(ti * 64 + row) * (Hq * HDq) + f4]);
      }
      if (lane < 16)
        dkw = *reinterpret_cast<const uint32*>(&dkb[dkbase + ti * 64 + lane * 4]);
    }
    __syncthreads();
    if (active) {
      const int lim = (ti == qt) ? lane : 63;
      for (int kk = 0; kk < 64; kk++) {
        uint32 dwrd = __shfl(dkw, kk >> 2, 64);
        uint32 db = (dwrd >> ((kk & 3) * 8)) & 0xFFu;
        uint32 x = myd ^ db;
        float wt = x ? (float)(x & (0u - x)) : 256.f;
        wt = (kk <= lim) ? wt : 0.f;
        den += wt;
        const float4* vrow = reinterpret_cast<const float4*>(&vs[wid][kk][0]);
#pragma unroll
        for (int d4 = 0; d4 < 16; d4++) {
          float4 vv = vrow[d4];
          num[d4 * 4 + 0] = fmaf(wt, vv.x, num[d4 * 4 + 0]);
          num[d4 * 4 + 1] = fmaf(wt, vv.y, num[d4 * 4 + 1]);
          num[d4 * 4 + 2] = fmaf(wt, vv.z, num[d4 * 4 + 2]);
          num[d4 * 4 + 3] = fmaf(wt, vv.w, num[d4 * 4 + 3]);
        }
      }
    }
    __syncthreads();
  }

  // cross-wave reduce: write partials transposed [d][q] (conflict-free)
#pragma unroll
  for (int d = 0; d < 64; d++) vs[wid][d][lane] = num[d];
  __syncthreads();
  float ys[16];
#pragma unroll
  for (int r2 = 0; r2 < 16; r2++) {
    int flat = t + (r2 << 8);
    int d = flat & 63, qq = flat >> 6;
    ys[r2] = vs[0][d][qq] + vs[1][d][qq] + vs[2][d][qq] + vs[3][d][qq];
  }
  __syncthreads();
  float* dsh = &vs[0][0][0];
  dsh[wid * 64 + lane] = den;
  __syncthreads();
#pragma unroll
  for (int r2 = 0; r2 < 16; r2++) {
    int flat = t + (r2 << 8);
    int d = flat & 63, qq = flat >> 6;
    float dn = dsh[qq] + dsh[64 + qq] + dsh[128 + qq] + dsh[192 + qq];
    y[((size_t)(b * Tq + qbase + qq) * Hq + h) * HDq + d] = ys[r2] / fmaxf(dn, 1e-9f);
  }
}

// --------------------------------------------------------------------------
extern "C" void kernel_launch(void* const* d_in, const int* in_sizes, int n_in,
                              void* d_out, int out_size, void* d_ws, size_t ws_size,
                              hipStream_t stream)
{
  const float* x    = (const float*)d_in[0];
  const float* cosT = (const float*)d_in[1];
  const float* sinT = (const float*)d_in[2];
  const float* Wq   = (const float*)d_in[3];
  const float* Wk   = (const float*)d_in[4];
  const float* Wv   = (const float*)d_in[5];
  const float* Wpr  = (const float*)d_in[6];
  const float* Wdq  = (const float*)d_in[7];
  const float* Wdk  = (const float*)d_in[8];
  float* out = (float*)d_out;

  const size_t NE = (size_t)Bq * Tq * Cq;   // 2 M floats each
  float* q = (float*)d_ws;
  float* k = q + NE;
  float* v = k + NE;
  float* y = v + NE;
  uint8_t* dqb = (uint8_t*)(y + NE);
  uint8_t* dkb = dqb + (size_t)Bq * Hq * Tq;

  const int M = Bq * Tq, N = Cq, K = Cq;

  gemm3_f32<<<dim3(M / 128, N / 64, 3), 256, 0, stream>>>(
      x, Wq, Wk, Wv, q, k, v, M, N, K);
  digits_kernel<<<dim3((Bq * Tq * Hq) / 8), 256, 0, stream>>>(
      q, k, cosT, sinT, Wdq, Wdk, dqb, dkb);
  attn_dense<<<dim3(Tq / 64, Hq, Bq), 256, 0, stream>>>(v, dqb, dkb, y);
  gemm3_f32<<<dim3(M / 128, N / 64, 1), 256, 0, stream>>>(
      y, Wpr, Wpr, Wpr, out, out, out, M, N, K);
}

// Round 4
// 218.981 us; speedup vs baseline: 1.7763x; 1.7763x over previous
//
#include <hip/hip_runtime.h>
#include <stdint.h>

#define Bq 2
#define Tq 1024
#define Cq 1024
#define Hq 16
#define HDq 64

typedef unsigned int uint32;
typedef __attribute__((ext_vector_type(8))) short bf16x8;
typedef __attribute__((ext_vector_type(4))) float f32x4;

__device__ __forceinline__ short f2bf(float x) {
  union { float f; uint32 u; } v; v.f = x;
  uint32 r = (v.u + 0x7FFFu + ((v.u >> 16) & 1u)) >> 16;
  return (short)r;
}
__device__ __forceinline__ float bf2f(short h) {
  union { uint32 u; float f; } v; v.u = ((uint32)(unsigned short)h) << 16;
  return v.f;
}
__device__ __forceinline__ void gload16(const short* g, short* l) {
  __builtin_amdgcn_global_load_lds(
      (const __attribute__((address_space(1))) unsigned int*)g,
      (__attribute__((address_space(3))) unsigned int*)l, 16, 0, 0);
}
__device__ __forceinline__ f32x4 mfma16(bf16x8 a, bf16x8 b, f32x4 c) {
  return __builtin_amdgcn_mfma_f32_16x16x32_bf16(a, b, c, 0, 0, 0);
}

// ---- pack rows of f32 [M][K] into NS bf16 planes, MFMA-A-operand order ----
// plane layout: [mt][kt][lane][8] bf16, m = mt*16+(lane&15), k = kt*32+(lane>>4)*8+j
template<int NS>
__global__ __launch_bounds__(256) void pack_rows(
    const float* __restrict__ A, short* __restrict__ P0,
    short* __restrict__ P1, short* __restrict__ P2, int M, int K)
{
  const int tg = blockIdx.x * 256 + threadIdx.x;
  const int lane = tg & 63, chunk = tg >> 6;
  const int KT = K >> 5;
  const int mt = chunk / KT, kt = chunk % KT;
  const int m = mt * 16 + (lane & 15);
  const int k = kt * 32 + ((lane >> 4) << 3);
  float4 v0 = *reinterpret_cast<const float4*>(&A[(size_t)m * K + k]);
  float4 v1 = *reinterpret_cast<const float4*>(&A[(size_t)m * K + k + 4]);
  float a[8] = {v0.x, v0.y, v0.z, v0.w, v1.x, v1.y, v1.z, v1.w};
  bf16x8 o0, o1, o2;
#pragma unroll
  for (int j = 0; j < 8; ++j) {
    short h1 = f2bf(a[j]); o0[j] = h1;
    if constexpr (NS == 3) {
      float r1 = a[j] - bf2f(h1);
      short h2 = f2bf(r1); o1[j] = h2;
      o2[j] = f2bf(r1 - bf2f(h2));
    }
  }
  size_t off = (size_t)tg * 8;
  *reinterpret_cast<bf16x8*>(&P0[off]) = o0;
  if constexpr (NS == 3) {
    *reinterpret_cast<bf16x8*>(&P1[off]) = o1;
    *reinterpret_cast<bf16x8*>(&P2[off]) = o2;
  }
}

// ---- split W [K][N] f32 into NS bf16 planes, transposed MFMA-B order ------
// plane layout: [nt][kt][lane][8], n = nt*16+(lane&15), k = kt*32+(lane>>4)*8+j
template<int NS>
__global__ __launch_bounds__(256) void presplit_w(
    const float* __restrict__ W, short* __restrict__ P0,
    short* __restrict__ P1, short* __restrict__ P2, int N, int K)
{
  __shared__ float ws_[64][65];
  const int t = threadIdx.x;
  const int n0 = blockIdx.x * 64, k0 = blockIdx.y * 64;
  const int KT = K >> 5;
#pragma unroll
  for (int pass = 0; pass < 4; ++pass) {
    int f = pass * 256 + t;
    int r = f >> 4, c4 = (f & 15) << 2;
    float4 vv = *reinterpret_cast<const float4*>(&W[(size_t)(k0 + r) * N + n0 + c4]);
    ws_[r][c4 + 0] = vv.x; ws_[r][c4 + 1] = vv.y;
    ws_[r][c4 + 2] = vv.z; ws_[r][c4 + 3] = vv.w;
  }
  __syncthreads();
#pragma unroll
  for (int s = 0; s < 2; ++s) {
    int slot = s * 256 + t;
    int lane = slot & 63, u = slot >> 6;      // u in 0..7
    int ntl = u >> 1, ktl = u & 1;
    int nl = ntl * 16 + (lane & 15);
    int kb = ktl * 32 + ((lane >> 4) << 3);
    bf16x8 o0, o1, o2;
#pragma unroll
    for (int j = 0; j < 8; ++j) {
      float a = ws_[kb + j][nl];
      short h1 = f2bf(a); o0[j] = h1;
      if constexpr (NS == 3) {
        float r1 = a - bf2f(h1);
        short h2 = f2bf(r1); o1[j] = h2;
        o2[j] = f2bf(r1 - bf2f(h2));
      }
    }
    size_t nt = (size_t)blockIdx.x * 4 + ntl;
    size_t kt = (size_t)blockIdx.y * 2 + ktl;
    size_t off = ((nt * KT + kt) * 64 + lane) * 8;
    *reinterpret_cast<bf16x8*>(&P0[off]) = o0;
    if constexpr (NS == 3) {
      *reinterpret_cast<bf16x8*>(&P1[off]) = o1;
      *reinterpret_cast<bf16x8*>(&P2[off]) = o2;
    }
  }
}

// ---- MFMA GEMM on packed planes. NS=1 plain bf16; NS=3 -> 6-term bf16x3 ---
// BM=128, BN=64, BK=32; 256 thr = 4 waves (2x2); wave tile 64x32 (4x2 frags).
template<int NS>
__global__ __launch_bounds__(256) void gemm_packed(
    const short* __restrict__ A0, const short* __restrict__ A1, const short* __restrict__ A2,
    const short* __restrict__ Bq0, const short* __restrict__ Bq1, const short* __restrict__ Bq2,
    const short* __restrict__ Bk0, const short* __restrict__ Bk1, const short* __restrict__ Bk2,
    float* __restrict__ C0, float* __restrict__ C1, int M, int N, int K)
{
  constexpr int CH = 12 * NS;          // 1024B chunks per buffer (8NS A + 4NS B)
  constexpr int BUF = CH * 512;        // shorts per buffer
  __shared__ short sm[2 * BUF];
  const int t = threadIdx.x, wid = t >> 6, lane = t & 63;
  const int wr = wid >> 1, wc = wid & 1;
  const int bx = blockIdx.x, by = blockIdx.y, z = blockIdx.z;
  const int KT = K >> 5;
  const short* Ap[3] = {A0, A1, A2};
  const short* Bp[3];
  if (z == 0) { Bp[0] = Bq0; Bp[1] = Bq1; Bp[2] = Bq2; }
  else        { Bp[0] = Bk0; Bp[1] = Bk1; Bp[2] = Bk2; }
  float* __restrict__ C = z ? C1 : C0;

  // slab stride per mt/nt tile = KT kt-tiles * 64 lanes * 8 shorts = KT*512
  const short* gb[3 * NS]; int lof[3 * NS];
#pragma unroll
  for (int i = 0; i < 3 * NS; ++i) {
    int c = wid * 3 * NS + i;
    if (c < 8 * NS) {
      int p = c >> 3, mtl = c & 7;
      gb[i] = Ap[p] + ((size_t)(bx * 8 + mtl) * KT * 512 + lane * 8);
      lof[i] = c * 512;                 // wave-uniform LDS base; HW adds lane*16B
    } else {
      int c2 = c - 8 * NS; int p = c2 >> 2, ntl = c2 & 3;
      gb[i] = Bp[p] + ((size_t)(by * 4 + ntl) * KT * 512 + lane * 8);
      lof[i] = (8 * NS + c2) * 512;
    }
  }

  f32x4 acc[4][2];
#pragma unroll
  for (int fr = 0; fr < 4; ++fr)
#pragma unroll
    for (int fc = 0; fc < 2; ++fc) acc[fr][fc] = (f32x4){0.f, 0.f, 0.f, 0.f};

#pragma unroll
  for (int i = 0; i < 3 * NS; ++i) gload16(gb[i], &sm[lof[i]]);

  int cur = 0;
  for (int kt = 0; kt < KT; ++kt) {
    __syncthreads();                       // drains vmcnt -> buf[cur] ready
    if (kt + 1 < KT) {
#pragma unroll
      for (int i = 0; i < 3 * NS; ++i)
        gload16(gb[i] + (size_t)(kt + 1) * 512, &sm[(cur ^ 1) * BUF + lof[i]]);
    }
    const short* sa = &sm[cur * BUF];
    const short* sbb = sa + 8 * NS * 512;
    bf16x8 af[NS][4], bfr[NS][2];
#pragma unroll
    for (int p = 0; p < NS; ++p)
#pragma unroll
      for (int fr = 0; fr < 4; ++fr)
        af[p][fr] = *reinterpret_cast<const bf16x8*>(sa + (p * 8 + wr * 4 + fr) * 512 + lane * 8);
#pragma unroll
    for (int p = 0; p < NS; ++p)
#pragma unroll
      for (int fc = 0; fc < 2; ++fc)
        bfr[p][fc] = *reinterpret_cast<const bf16x8*>(sbb + (p * 4 + wc * 2 + fc) * 512 + lane * 8);
#pragma unroll
    for (int fr = 0; fr < 4; ++fr)
#pragma unroll
      for (int fc = 0; fc < 2; ++fc) {
        acc[fr][fc] = mfma16(af[0][fr], bfr[0][fc], acc[fr][fc]);
        if constexpr (NS == 3) {
          acc[fr][fc] = mfma16(af[0][fr], bfr[1][fc], acc[fr][fc]);
          acc[fr][fc] = mfma16(af[1][fr], bfr[0][fc], acc[fr][fc]);
          acc[fr][fc] = mfma16(af[1][fr], bfr[1][fc], acc[fr][fc]);
          acc[fr][fc] = mfma16(af[0][fr], bfr[2][fc], acc[fr][fc]);
          acc[fr][fc] = mfma16(af[2][fr], bfr[0][fc], acc[fr][fc]);
        }
      }
    cur ^= 1;
  }

  const int rb = bx * 128 + wr * 64 + ((lane >> 4) << 2);
  const int cb = by * 64 + wc * 32 + (lane & 15);
#pragma unroll
  for (int fr = 0; fr < 4; ++fr)
#pragma unroll
    for (int fc = 0; fc < 2; ++fc)
#pragma unroll
      for (int r = 0; r < 4; ++r)
        C[(size_t)(rb + fr * 16 + r) * N + cb + fc * 16] = acc[fr][fc][r];
}

// ---------------- RoPE + RMS + hard digits (unchanged) --------------------
__global__ __launch_bounds__(256) void digits_kernel(
    const float* __restrict__ q, const float* __restrict__ k,
    const float* __restrict__ cosT, const float* __restrict__ sinT,
    const float* __restrict__ Wdq, const float* __restrict__ Wdk,
    uint8_t* __restrict__ dqb, uint8_t* __restrict__ dkb)
{
  const int t = threadIdx.x;
  const int lane = t & 31;
  const int u = blockIdx.x * 8 + (t >> 5);     // (b*T + tt)*H + h
  const int h = u & (Hq - 1);
  const int tt = (u >> 4) & (Tq - 1);
  const int b = u >> 14;
  const size_t base = (size_t)u * HDq;
  const float c = cosT[tt * 32 + lane];
  const float s = sinT[tt * 32 + lane];
  {
    float x1 = q[base + lane], x2 = q[base + lane + 32];
    float r1 = x1 * c + x2 * s;
    float r2 = x2 * c - x1 * s;
    float ss = r1 * r1 + r2 * r2;
#pragma unroll
    for (int off = 16; off; off >>= 1) ss += __shfl_xor(ss, off, 32);
    float inv = rsqrtf(ss * (1.f / 64.f) + 1e-6f);
    r1 *= inv; r2 *= inv;
    uint32 bits = 0;
#pragma unroll
    for (int j = 0; j < 8; j++) {
      float p = r1 * Wdq[lane * 8 + j] + r2 * Wdq[(lane + 32) * 8 + j];
#pragma unroll
      for (int off = 16; off; off >>= 1) p += __shfl_xor(p, off, 32);
      bits |= (p > 0.f ? 1u : 0u) << j;
    }
    if (lane == 0) dqb[((size_t)b * Hq + h) * Tq + tt] = (uint8_t)bits;
  }
  {
    float x1 = k[base + lane], x2 = k[base + lane + 32];
    float r1 = x1 * c + x2 * s;
    float r2 = x2 * c - x1 * s;
    float ss = r1 * r1 + r2 * r2;
#pragma unroll
    for (int off = 16; off; off >>= 1) ss += __shfl_xor(ss, off, 32);
    float inv = rsqrtf(ss * (1.f / 64.f) + 1e-6f);
    r1 *= inv; r2 *= inv;
    uint32 bits = 0;
#pragma unroll
    for (int j = 0; j < 8; j++) {
      float p = r1 * Wdk[lane * 8 + j] + r2 * Wdk[(lane + 32) * 8 + j];
#pragma unroll
      for (int off = 16; off; off >>= 1) p += __shfl_xor(p, off, 32);
      bits |= (p > 0.f ? 1u : 0u) << j;
    }
    if (lane == 0) dkb[((size_t)b * Hq + h) * Tq + tt] = (uint8_t)bits;
  }
}

// ---------------- dense causal ultrametric attention (unchanged) ----------
__global__ __launch_bounds__(256) void attn_dense(
    const float* __restrict__ v, const uint8_t* __restrict__ dqb,
    const uint8_t* __restrict__ dkb, float* __restrict__ y)
{
  __shared__ float vs[4][64][64];
  const int t = threadIdx.x;
  const int wid = t >> 6;
  const int lane = t & 63;
  const int qt = blockIdx.x, h = blockIdx.y, b = blockIdx.z;
  const int qbase = qt * 64;
  const int q = qbase + lane;
  const uint32 myd = dqb[((size_t)b * Hq + h) * Tq + q];
  const size_t vbh = ((size_t)b * Tq * Hq + h) * HDq;
  const size_t dkbase = ((size_t)b * Hq + h) * Tq;
  float num[64];
#pragma unroll
  for (int d = 0; d < 64; d++) num[d] = 0.f;
  float den = 0.f;
  const int ntiles = qt + 1;
  const int rounds = (ntiles + 3) >> 2;

  for (int r = 0; r < rounds; r++) {
    const int ti = r * 4 + wid;
    const bool active = ti < ntiles;
    uint32 dkw = 0;
    if (active) {
#pragma unroll
      for (int it = 0; it < 16; it++) {
        int row = it * 4 + (lane >> 4);
        int f4 = (lane & 15) << 2;
        *reinterpret_cast<float4*>(&vs[wid][row][f4]) =
            *reinterpret_cast<const float4*>(
                &v[vbh + (size_t)(ti * 64 + row) * (Hq * HDq) + f4]);
      }
      if (lane < 16)
        dkw = *reinterpret_cast<const uint32*>(&dkb[dkbase + ti * 64 + lane * 4]);
    }
    __syncthreads();
    if (active) {
      const int lim = (ti == qt) ? lane : 63;
      for (int kk = 0; kk < 64; kk++) {
        uint32 dwrd = __shfl(dkw, kk >> 2, 64);
        uint32 db = (dwrd >> ((kk & 3) * 8)) & 0xFFu;
        uint32 x = myd ^ db;
        float wt = x ? (float)(x & (0u - x)) : 256.f;
        wt = (kk <= lim) ? wt : 0.f;
        den += wt;
        const float4* vrow = reinterpret_cast<const float4*>(&vs[wid][kk][0]);
#pragma unroll
        for (int d4 = 0; d4 < 16; d4++) {
          float4 vv = vrow[d4];
          num[d4 * 4 + 0] = fmaf(wt, vv.x, num[d4 * 4 + 0]);
          num[d4 * 4 + 1] = fmaf(wt, vv.y, num[d4 * 4 + 1]);
          num[d4 * 4 + 2] = fmaf(wt, vv.z, num[d4 * 4 + 2]);
          num[d4 * 4 + 3] = fmaf(wt, vv.w, num[d4 * 4 + 3]);
        }
      }
    }
    __syncthreads();
  }

#pragma unroll
  for (int d = 0; d < 64; d++) vs[wid][d][lane] = num[d];
  __syncthreads();
  float ys[16];
#pragma unroll
  for (int r2 = 0; r2 < 16; r2++) {
    int flat = t + (r2 << 8);
    int d = flat & 63, qq = flat >> 6;
    ys[r2] = vs[0][d][qq] + vs[1][d][qq] + vs[2][d][qq] + vs[3][d][qq];
  }
  __syncthreads();
  float* dsh = &vs[0][0][0];
  dsh[wid * 64 + lane] = den;
  __syncthreads();
#pragma unroll
  for (int r2 = 0; r2 < 16; r2++) {
    int flat = t + (r2 << 8);
    int d = flat & 63, qq = flat >> 6;
    float dn = dsh[qq] + dsh[64 + qq] + dsh[128 + qq] + dsh[192 + qq];
    y[((size_t)(b * Tq + qbase + qq) * Hq + h) * HDq + d] = ys[r2] / fmaxf(dn, 1e-9f);
  }
}

// --------------------------------------------------------------------------
extern "C" void kernel_launch(void* const* d_in, const int* in_sizes, int n_in,
                              void* d_out, int out_size, void* d_ws, size_t ws_size,
                              hipStream_t stream)
{
  const float* x    = (const float*)d_in[0];
  const float* cosT = (const float*)d_in[1];
  const float* sinT = (const float*)d_in[2];
  const float* Wq   = (const float*)d_in[3];
  const float* Wk   = (const float*)d_in[4];
  const float* Wv   = (const float*)d_in[5];
  const float* Wpr  = (const float*)d_in[6];
  const float* Wdq  = (const float*)d_in[7];
  const float* Wdk  = (const float*)d_in[8];
  float* out = (float*)d_out;

  const size_t MB = (size_t)1 << 20;
  char* w = (char*)d_ws;
  float* q   = (float*)(w + 0 * MB);
  float* k   = (float*)(w + 8 * MB);
  float* v   = (float*)(w + 16 * MB);
  short* xp0 = (short*)(w + 24 * MB);
  short* xp1 = (short*)(w + 28 * MB);
  short* xp2 = (short*)(w + 32 * MB);
  short* wq0 = (short*)(w + 36 * MB);
  short* wq1 = (short*)(w + 38 * MB);
  short* wq2 = (short*)(w + 40 * MB);
  short* wk0 = (short*)(w + 42 * MB);
  short* wk1 = (short*)(w + 44 * MB);
  short* wk2 = (short*)(w + 46 * MB);
  short* wv_ = (short*)(w + 48 * MB);
  short* wp_ = (short*)(w + 50 * MB);
  uint8_t* dqb = (uint8_t*)(w + 52 * MB);
  uint8_t* dkb = dqb + (size_t)Bq * Hq * Tq;
  float* y = k;            // k is dead after digits_kernel
  short* yp = (short*)q;   // q is dead after digits_kernel

  const int M = Bq * Tq, N = Cq, K = Cq;

  pack_rows<3><<<1024, 256, 0, stream>>>(x, xp0, xp1, xp2, M, K);
  presplit_w<3><<<dim3(16, 16), 256, 0, stream>>>(Wq, wq0, wq1, wq2, N, K);
  presplit_w<3><<<dim3(16, 16), 256, 0, stream>>>(Wk, wk0, wk1, wk2, N, K);
  presplit_w<1><<<dim3(16, 16), 256, 0, stream>>>(Wv, wv_, wv_, wv_, N, K);
  presplit_w<1><<<dim3(16, 16), 256, 0, stream>>>(Wpr, wp_, wp_, wp_, N, K);

  gemm_packed<3><<<dim3(16, 16, 2), 256, 0, stream>>>(
      xp0, xp1, xp2, wq0, wq1, wq2, wk0, wk1, wk2, q, k, M, N, K);
  gemm_packed<1><<<dim3(16, 16, 1), 256, 0, stream>>>(
      xp0, xp0, xp0, wv_, wv_, wv_, wv_, wv_, wv_, v, v, M, N, K);

  digits_kernel<<<4096, 256, 0, stream>>>(q, k, cosT, sinT, Wdq, Wdk, dqb, dkb);
  attn_dense<<<dim3(16, 16, 2), 256, 0, stream>>>(v, dqb, dkb, y);

  pack_rows<1><<<1024, 256, 0, stream>>>(y, yp, yp, yp, M, K);
  gemm_packed<1><<<dim3(16, 16, 1), 256, 0, stream>>>(
      yp, yp, yp, wp_, wp_, wp_, wp_, wp_, wp_, out, out, M, N, K);
}

// Round 5
// 160.384 us; speedup vs baseline: 2.4252x; 1.3654x over previous
//
#include <hip/hip_runtime.h>
#include <stdint.h>

#define Bq 2
#define Tq 1024
#define Cq 1024
#define Hq 16
#define HDq 64

typedef unsigned int uint32;
typedef __attribute__((ext_vector_type(8))) short bf16x8;
typedef __attribute__((ext_vector_type(4))) float f32x4;

__device__ __forceinline__ short f2bf(float x) {
  union { float f; uint32 u; } v; v.f = x;
  uint32 r = (v.u + 0x7FFFu + ((v.u >> 16) & 1u)) >> 16;
  return (short)r;
}
__device__ __forceinline__ float bf2f(short h) {
  union { uint32 u; float f; } v; v.u = ((uint32)(unsigned short)h) << 16;
  return v.f;
}
__device__ __forceinline__ void gload16(const short* g, short* l) {
  __builtin_amdgcn_global_load_lds(
      (const __attribute__((address_space(1))) unsigned int*)g,
      (__attribute__((address_space(3))) unsigned int*)l, 16, 0, 0);
}
__device__ __forceinline__ f32x4 mfma16(bf16x8 a, bf16x8 b, f32x4 c) {
  return __builtin_amdgcn_mfma_f32_16x16x32_bf16(a, b, c, 0, 0, 0);
}

// ---- pack rows of f32 [M][K] into NS bf16 planes, MFMA-A-operand order ----
// plane layout: [mt][kt][lane][8] bf16, m = mt*16+(lane&15), k = kt*32+(lane>>4)*8+j
template<int NS>
__global__ __launch_bounds__(256) void pack_rows(
    const float* __restrict__ A, short* __restrict__ P0,
    short* __restrict__ P1, short* __restrict__ P2, int M, int K)
{
  const int tg = blockIdx.x * 256 + threadIdx.x;
  const int lane = tg & 63, chunk = tg >> 6;
  const int KT = K >> 5;
  const int mt = chunk / KT, kt = chunk % KT;
  const int m = mt * 16 + (lane & 15);
  const int k = kt * 32 + ((lane >> 4) << 3);
  float4 v0 = *reinterpret_cast<const float4*>(&A[(size_t)m * K + k]);
  float4 v1 = *reinterpret_cast<const float4*>(&A[(size_t)m * K + k + 4]);
  float a[8] = {v0.x, v0.y, v0.z, v0.w, v1.x, v1.y, v1.z, v1.w};
  bf16x8 o0, o1, o2;
#pragma unroll
  for (int j = 0; j < 8; ++j) {
    short h1 = f2bf(a[j]); o0[j] = h1;
    if constexpr (NS == 3) {
      float r1 = a[j] - bf2f(h1);
      short h2 = f2bf(r1); o1[j] = h2;
      o2[j] = f2bf(r1 - bf2f(h2));
    }
  }
  size_t off = (size_t)tg * 8;
  *reinterpret_cast<bf16x8*>(&P0[off]) = o0;
  if constexpr (NS == 3) {
    *reinterpret_cast<bf16x8*>(&P1[off]) = o1;
    *reinterpret_cast<bf16x8*>(&P2[off]) = o2;
  }
}

// ---- split W [K][N] f32 into NS bf16 planes, transposed MFMA-B order ------
template<int NS>
__global__ __launch_bounds__(256) void presplit_w(
    const float* __restrict__ W, short* __restrict__ P0,
    short* __restrict__ P1, short* __restrict__ P2, int N, int K)
{
  __shared__ float ws_[64][65];
  const int t = threadIdx.x;
  const int n0 = blockIdx.x * 64, k0 = blockIdx.y * 64;
  const int KT = K >> 5;
#pragma unroll
  for (int pass = 0; pass < 4; ++pass) {
    int f = pass * 256 + t;
    int r = f >> 4, c4 = (f & 15) << 2;
    float4 vv = *reinterpret_cast<const float4*>(&W[(size_t)(k0 + r) * N + n0 + c4]);
    ws_[r][c4 + 0] = vv.x; ws_[r][c4 + 1] = vv.y;
    ws_[r][c4 + 2] = vv.z; ws_[r][c4 + 3] = vv.w;
  }
  __syncthreads();
#pragma unroll
  for (int s = 0; s < 2; ++s) {
    int slot = s * 256 + t;
    int lane = slot & 63, u = slot >> 6;
    int ntl = u >> 1, ktl = u & 1;
    int nl = ntl * 16 + (lane & 15);
    int kb = ktl * 32 + ((lane >> 4) << 3);
    bf16x8 o0, o1, o2;
#pragma unroll
    for (int j = 0; j < 8; ++j) {
      float a = ws_[kb + j][nl];
      short h1 = f2bf(a); o0[j] = h1;
      if constexpr (NS == 3) {
        float r1 = a - bf2f(h1);
        short h2 = f2bf(r1); o1[j] = h2;
        o2[j] = f2bf(r1 - bf2f(h2));
      }
    }
    size_t nt = (size_t)blockIdx.x * 4 + ntl;
    size_t kt = (size_t)blockIdx.y * 2 + ktl;
    size_t off = ((nt * KT + kt) * 64 + lane) * 8;
    *reinterpret_cast<bf16x8*>(&P0[off]) = o0;
    if constexpr (NS == 3) {
      *reinterpret_cast<bf16x8*>(&P1[off]) = o1;
      *reinterpret_cast<bf16x8*>(&P2[off]) = o2;
    }
  }
}

// ---- MFMA GEMM on packed planes (verified round 4) ------------------------
template<int NS>
__global__ __launch_bounds__(256) void gemm_packed(
    const short* __restrict__ A0, const short* __restrict__ A1, const short* __restrict__ A2,
    const short* __restrict__ Bq0, const short* __restrict__ Bq1, const short* __restrict__ Bq2,
    const short* __restrict__ Bk0, const short* __restrict__ Bk1, const short* __restrict__ Bk2,
    float* __restrict__ C0, float* __restrict__ C1, int M, int N, int K)
{
  constexpr int CH = 12 * NS;
  constexpr int BUF = CH * 512;
  __shared__ short sm[2 * BUF];
  const int t = threadIdx.x, wid = t >> 6, lane = t & 63;
  const int wr = wid >> 1, wc = wid & 1;
  const int bx = blockIdx.x, by = blockIdx.y, z = blockIdx.z;
  const int KT = K >> 5;
  const short* Ap[3] = {A0, A1, A2};
  const short* Bp[3];
  if (z == 0) { Bp[0] = Bq0; Bp[1] = Bq1; Bp[2] = Bq2; }
  else        { Bp[0] = Bk0; Bp[1] = Bk1; Bp[2] = Bk2; }
  float* __restrict__ C = z ? C1 : C0;

  const short* gb[3 * NS]; int lof[3 * NS];
#pragma unroll
  for (int i = 0; i < 3 * NS; ++i) {
    int c = wid * 3 * NS + i;
    if (c < 8 * NS) {
      int p = c >> 3, mtl = c & 7;
      gb[i] = Ap[p] + ((size_t)(bx * 8 + mtl) * KT * 512 + lane * 8);
      lof[i] = c * 512;
    } else {
      int c2 = c - 8 * NS; int p = c2 >> 2, ntl = c2 & 3;
      gb[i] = Bp[p] + ((size_t)(by * 4 + ntl) * KT * 512 + lane * 8);
      lof[i] = (8 * NS + c2) * 512;
    }
  }

  f32x4 acc[4][2];
#pragma unroll
  for (int fr = 0; fr < 4; ++fr)
#pragma unroll
    for (int fc = 0; fc < 2; ++fc) acc[fr][fc] = (f32x4){0.f, 0.f, 0.f, 0.f};

#pragma unroll
  for (int i = 0; i < 3 * NS; ++i) gload16(gb[i], &sm[lof[i]]);

  int cur = 0;
  for (int kt = 0; kt < KT; ++kt) {
    __syncthreads();
    if (kt + 1 < KT) {
#pragma unroll
      for (int i = 0; i < 3 * NS; ++i)
        gload16(gb[i] + (size_t)(kt + 1) * 512, &sm[(cur ^ 1) * BUF + lof[i]]);
    }
    const short* sa = &sm[cur * BUF];
    const short* sbb = sa + 8 * NS * 512;
    bf16x8 af[NS][4], bfr[NS][2];
#pragma unroll
    for (int p = 0; p < NS; ++p)
#pragma unroll
      for (int fr = 0; fr < 4; ++fr)
        af[p][fr] = *reinterpret_cast<const bf16x8*>(sa + (p * 8 + wr * 4 + fr) * 512 + lane * 8);
#pragma unroll
    for (int p = 0; p < NS; ++p)
#pragma unroll
      for (int fc = 0; fc < 2; ++fc)
        bfr[p][fc] = *reinterpret_cast<const bf16x8*>(sbb + (p * 4 + wc * 2 + fc) * 512 + lane * 8);
#pragma unroll
    for (int fr = 0; fr < 4; ++fr)
#pragma unroll
      for (int fc = 0; fc < 2; ++fc) {
        acc[fr][fc] = mfma16(af[0][fr], bfr[0][fc], acc[fr][fc]);
        if constexpr (NS == 3) {
          acc[fr][fc] = mfma16(af[0][fr], bfr[1][fc], acc[fr][fc]);
          acc[fr][fc] = mfma16(af[1][fr], bfr[0][fc], acc[fr][fc]);
          acc[fr][fc] = mfma16(af[1][fr], bfr[1][fc], acc[fr][fc]);
          acc[fr][fc] = mfma16(af[0][fr], bfr[2][fc], acc[fr][fc]);
          acc[fr][fc] = mfma16(af[2][fr], bfr[0][fc], acc[fr][fc]);
        }
      }
    cur ^= 1;
  }

  const int rb = bx * 128 + wr * 64 + ((lane >> 4) << 2);
  const int cb = by * 64 + wc * 32 + (lane & 15);
#pragma unroll
  for (int fr = 0; fr < 4; ++fr)
#pragma unroll
    for (int fc = 0; fc < 2; ++fc)
#pragma unroll
      for (int r = 0; r < 4; ++r)
        C[(size_t)(rb + fr * 16 + r) * N + cb + fc * 16] = acc[fr][fc][r];
}

// ---- RoPE + RMS + hard digits (unchanged) --------------------------------
__global__ __launch_bounds__(256) void digits_kernel(
    const float* __restrict__ q, const float* __restrict__ k,
    const float* __restrict__ cosT, const float* __restrict__ sinT,
    const float* __restrict__ Wdq, const float* __restrict__ Wdk,
    uint8_t* __restrict__ dqb, uint8_t* __restrict__ dkb)
{
  const int t = threadIdx.x;
  const int lane = t & 31;
  const int u = blockIdx.x * 8 + (t >> 5);
  const int h = u & (Hq - 1);
  const int tt = (u >> 4) & (Tq - 1);
  const int b = u >> 14;
  const size_t base = (size_t)u * HDq;
  const float c = cosT[tt * 32 + lane];
  const float s = sinT[tt * 32 + lane];
  {
    float x1 = q[base + lane], x2 = q[base + lane + 32];
    float r1 = x1 * c + x2 * s;
    float r2 = x2 * c - x1 * s;
    float ss = r1 * r1 + r2 * r2;
#pragma unroll
    for (int off = 16; off; off >>= 1) ss += __shfl_xor(ss, off, 32);
    float inv = rsqrtf(ss * (1.f / 64.f) + 1e-6f);
    r1 *= inv; r2 *= inv;
    uint32 bits = 0;
#pragma unroll
    for (int j = 0; j < 8; j++) {
      float p = r1 * Wdq[lane * 8 + j] + r2 * Wdq[(lane + 32) * 8 + j];
#pragma unroll
      for (int off = 16; off; off >>= 1) p += __shfl_xor(p, off, 32);
      bits |= (p > 0.f ? 1u : 0u) << j;
    }
    if (lane == 0) dqb[((size_t)b * Hq + h) * Tq + tt] = (uint8_t)bits;
  }
  {
    float x1 = k[base + lane], x2 = k[base + lane + 32];
    float r1 = x1 * c + x2 * s;
    float r2 = x2 * c - x1 * s;
    float ss = r1 * r1 + r2 * r2;
#pragma unroll
    for (int off = 16; off; off >>= 1) ss += __shfl_xor(ss, off, 32);
    float inv = rsqrtf(ss * (1.f / 64.f) + 1e-6f);
    r1 *= inv; r2 *= inv;
    uint32 bits = 0;
#pragma unroll
    for (int j = 0; j < 8; j++) {
      float p = r1 * Wdk[lane * 8 + j] + r2 * Wdk[(lane + 32) * 8 + j];
#pragma unroll
      for (int off = 16; off; off >>= 1) p += __shfl_xor(p, off, 32);
      bits |= (p > 0.f ? 1u : 0u) << j;
    }
    if (lane == 0) dkb[((size_t)b * Hq + h) * Tq + tt] = (uint8_t)bits;
  }
}

// ---- pack V f32 [B,T,H*64] -> per-head MFMA-B-operand bf16 planes --------
// PV[b][h][nt(4)][kT(32)][lane(64)][8]: n = nt*16+(lane&15), k = kT*32+(lane>>4)*8+j
__global__ __launch_bounds__(256) void pack_v(
    const float* __restrict__ v, short* __restrict__ PV)
{
  const int tg = blockIdx.x * 256 + threadIdx.x;
  const int lane = tg & 63;
  const int kT = (tg >> 6) & 31;
  const int nt = (tg >> 11) & 3;
  const int h  = (tg >> 13) & 15;
  const int b  = tg >> 17;
  const int n = nt * 16 + (lane & 15);
  const int g = lane >> 4;
  bf16x8 o;
#pragma unroll
  for (int j = 0; j < 8; ++j) {
    float val = v[(size_t)(b * Tq + kT * 32 + g * 8 + j) * Cq + h * HDq + n];
    o[j] = f2bf(val);
  }
  *reinterpret_cast<bf16x8*>(&PV[(size_t)tg * 8]) = o;
}

// ---- MFMA ultrametric causal attention -----------------------------------
// block = 4 waves, one 64-query tile; wave w owns d-slice [w*16, w*16+16).
// W weights built in-register as exact bf16 powers of 2; den as exact ints.
__global__ __launch_bounds__(256) void attn_mfma(
    const short* __restrict__ PV, const uint8_t* __restrict__ dqb,
    const uint8_t* __restrict__ dkb, float* __restrict__ y)
{
  __shared__ short vbuf[2][4][2][512];          // 16 KB
  __shared__ __align__(16) uint32 dks4[256];    // up to 1024 dk bytes
  __shared__ float den_lds[64];
  const int t = threadIdx.x, wid = t >> 6, lane = t & 63;
  const int r = lane & 15, g = lane >> 4;
  const int qt = blockIdx.x, h = blockIdx.y, b = blockIdx.z;
  const int bh = b * Hq + h;
  const short* pvb = PV + ((size_t)bh * 4 + wid) * 32 * 512 + lane * 8;

  {  // stage dk digit bytes for key tiles 0..qt
    const uint32* src4 = (const uint32*)(dkb + (size_t)bh * Tq);
    if (t < (qt + 1) * 16) dks4[t] = src4[t];
  }
  const uint8_t* dq_tile = dqb + (size_t)bh * Tq + qt * 64;
  uint32 myq[4];
#pragma unroll
  for (int mt = 0; mt < 4; ++mt) myq[mt] = dq_tile[mt * 16 + r];

#pragma unroll
  for (int ks = 0; ks < 2; ++ks)               // prologue: stage kt=0
    gload16(pvb + (size_t)ks * 512, &vbuf[0][wid][ks][0]);

  f32x4 acc[4];
#pragma unroll
  for (int mt = 0; mt < 4; ++mt) acc[mt] = (f32x4){0.f, 0.f, 0.f, 0.f};
  uint32 den_i = 0;

  auto tile = [&](int kt, int db, bool MASK) {
    bf16x8 bfr[2];
#pragma unroll
    for (int ks = 0; ks < 2; ++ks)
      bfr[ks] = *reinterpret_cast<const bf16x8*>(&vbuf[db][wid][ks][lane * 8]);
    unsigned long long d8[2];
#pragma unroll
    for (int ks = 0; ks < 2; ++ks)
      d8[ks] = *reinterpret_cast<const unsigned long long*>(
          (const char*)dks4 + kt * 64 + ks * 32 + g * 8);
#pragma unroll
    for (int mt = 0; mt < 4; ++mt) {
      const uint32 dq = myq[mt];
      const int qrow = mt * 16 + r;
#pragma unroll
      for (int ks = 0; ks < 2; ++ks) {
        const int kbase = ks * 32 + g * 8;
        uint32 parts[4];
#pragma unroll
        for (int jj = 0; jj < 4; ++jj) {
          uint32 b0 = (uint32)(d8[ks] >> (16 * jj)) & 0xFFu;
          uint32 b1 = (uint32)(d8[ks] >> (16 * jj + 8)) & 0xFFu;
          uint32 e0 = (uint32)__builtin_ctz((dq ^ b0) | 0x100u);
          uint32 e1 = (uint32)__builtin_ctz((dq ^ b1) | 0x100u);
          uint32 w0 = 0x3F80u + (e0 << 7);     // bf16 bits of 2^e, exact
          uint32 w1 = 0x3F80u + (e1 << 7);
          if (MASK) {
            if (kbase + 2 * jj     > qrow) w0 = 0;
            if (kbase + 2 * jj + 1 > qrow) w1 = 0;
          }
          if (mt == wid) {                     // exact integer denominator
            den_i += (w0 ? (1u << e0) : 0u);
            den_i += (w1 ? (1u << e1) : 0u);
          }
          parts[jj] = w0 | (w1 << 16);
        }
        union { uint32 u[4]; bf16x8 v8; } cv;
        cv.u[0] = parts[0]; cv.u[1] = parts[1];
        cv.u[2] = parts[2]; cv.u[3] = parts[3];
        acc[mt] = mfma16(cv.v8, bfr[ks], acc[mt]);
      }
    }
  };

  int cur = 0;
  for (int kt = 0; kt < qt; ++kt) {
    __syncthreads();
#pragma unroll
    for (int ks = 0; ks < 2; ++ks)
      gload16(pvb + (size_t)((kt + 1) * 2 + ks) * 512, &vbuf[cur ^ 1][wid][ks][0]);
    tile(kt, cur, false);
    cur ^= 1;
  }
  __syncthreads();
  tile(qt, cur, true);                         // diagonal tile, causal-masked

  den_i += (uint32)__shfl_xor((int)den_i, 16, 64);
  den_i += (uint32)__shfl_xor((int)den_i, 32, 64);
  if (lane < 16) den_lds[wid * 16 + lane] = (float)den_i;
  __syncthreads();

  const int dglob = wid * 16 + r;
#pragma unroll
  for (int mt = 0; mt < 4; ++mt)
#pragma unroll
    for (int reg = 0; reg < 4; ++reg) {
      int qloc = mt * 16 + g * 4 + reg;
      float dn = den_lds[qloc];
      y[(size_t)(b * Tq + qt * 64 + qloc) * Cq + h * HDq + dglob] =
          acc[mt][reg] / fmaxf(dn, 1e-9f);
    }
}

// --------------------------------------------------------------------------
extern "C" void kernel_launch(void* const* d_in, const int* in_sizes, int n_in,
                              void* d_out, int out_size, void* d_ws, size_t ws_size,
                              hipStream_t stream)
{
  const float* x    = (const float*)d_in[0];
  const float* cosT = (const float*)d_in[1];
  const float* sinT = (const float*)d_in[2];
  const float* Wq   = (const float*)d_in[3];
  const float* Wk   = (const float*)d_in[4];
  const float* Wv   = (const float*)d_in[5];
  const float* Wpr  = (const float*)d_in[6];
  const float* Wdq  = (const float*)d_in[7];
  const float* Wdk  = (const float*)d_in[8];
  float* out = (float*)d_out;

  const size_t MB = (size_t)1 << 20;
  char* w = (char*)d_ws;
  float* q   = (float*)(w + 0 * MB);
  float* k   = (float*)(w + 8 * MB);
  float* v   = (float*)(w + 16 * MB);
  short* xp0 = (short*)(w + 24 * MB);
  short* xp1 = (short*)(w + 28 * MB);   // becomes PV after gemm<3>
  short* xp2 = (short*)(w + 32 * MB);
  short* wq0 = (short*)(w + 36 * MB);
  short* wq1 = (short*)(w + 38 * MB);
  short* wq2 = (short*)(w + 40 * MB);
  short* wk0 = (short*)(w + 42 * MB);
  short* wk1 = (short*)(w + 44 * MB);
  short* wk2 = (short*)(w + 46 * MB);
  short* wv_ = (short*)(w + 48 * MB);
  short* wp_ = (short*)(w + 50 * MB);
  uint8_t* dqb = (uint8_t*)(w + 52 * MB);
  uint8_t* dkb = dqb + (size_t)Bq * Hq * Tq;
  float* y  = k;           // k dead after digits_kernel
  short* yp = (short*)q;   // q dead after digits_kernel
  short* PV = xp1;         // xp1 dead after gemm<3>

  const int M = Bq * Tq, N = Cq, K = Cq;

  pack_rows<3><<<1024, 256, 0, stream>>>(x, xp0, xp1, xp2, M, K);
  presplit_w<3><<<dim3(16, 16), 256, 0, stream>>>(Wq, wq0, wq1, wq2, N, K);
  presplit_w<3><<<dim3(16, 16), 256, 0, stream>>>(Wk, wk0, wk1, wk2, N, K);
  presplit_w<1><<<dim3(16, 16), 256, 0, stream>>>(Wv, wv_, wv_, wv_, N, K);
  presplit_w<1><<<dim3(16, 16), 256, 0, stream>>>(Wpr, wp_, wp_, wp_, N, K);

  gemm_packed<3><<<dim3(16, 16, 2), 256, 0, stream>>>(
      xp0, xp1, xp2, wq0, wq1, wq2, wk0, wk1, wk2, q, k, M, N, K);
  gemm_packed<1><<<dim3(16, 16, 1), 256, 0, stream>>>(
      xp0, xp0, xp0, wv_, wv_, wv_, wv_, wv_, wv_, v, v, M, N, K);

  pack_v<<<1024, 256, 0, stream>>>(v, PV);
  digits_kernel<<<4096, 256, 0, stream>>>(q, k, cosT, sinT, Wdq, Wdk, dqb, dkb);
  attn_mfma<<<dim3(16, 16, 2), 256, 0, stream>>>(PV, dqb, dkb, y);

  pack_rows<1><<<1024, 256, 0, stream>>>(y, yp, yp, yp, M, K);
  gemm_packed<1><<<dim3(16, 16, 1), 256, 0, stream>>>(
      yp, yp, yp, wp_, wp_, wp_, wp_, wp_, wp_, out, out, M, N, K);
}